// Round 14
// baseline (2763.174 us; speedup 1.0000x reference)
//
#include <hip/hip_runtime.h>
#include <math.h>

// Problem constants (fixed by the reference)
#define BB 4
#define QQ 300
#define CC 256          // QUERY_DIM / hidden
#define NH 8
#define HD 32           // head dim
#define HWN 10000       // H*W
#define NT 625          // hw tiles of 16
#define NCHUNK 125      // hw chunks per (b,n)
#define TPC 5           // hw tiles per chunk (125*5=625)
#define MT 19           // q tiles of 16 (300 -> 304 via clamp)
#define NORM_FACT 0.17677669529663687f  // 32^-0.5

typedef __attribute__((ext_vector_type(8))) short short8_t;   // 8 bf16 (4 VGPR)
typedef __attribute__((ext_vector_type(4))) float f32x4_t;    // MFMA C/D
typedef __attribute__((ext_vector_type(4))) int   i32x4_t;

union FragU { uint32_t u[4]; short8_t v; };

__device__ __forceinline__ unsigned short bf16_rn(float x) {
    uint32_t u = __float_as_uint(x);
    return (unsigned short)((u + 0x7fffu + ((u >> 16) & 1u)) >> 16);
}
__device__ __forceinline__ float bf16_f(unsigned short h) {
    return __uint_as_float(((uint32_t)h) << 16);
}

// ---------------------------------------------------------------------------
// P0: pre-pack kw (split bf16) into kproj's exact B-fragment order.
// ---------------------------------------------------------------------------
__global__ void prep_kwB_kernel(const float* __restrict__ kw,
                                unsigned short* __restrict__ kwB_hi,
                                unsigned short* __restrict__ kwB_lo) {
    const int ot = blockIdx.x, ks = blockIdx.y;    // 16 x 8
    const int l = threadIdx.x;                     // 64
    const int o = ot * 16 + (l & 15);
    const int c0 = ks * 32 + (l >> 4) * 8;
    const size_t base = ((size_t)(ot * 8 + ks) * 64 + l) * 8;
    #pragma unroll
    for (int j = 0; j < 8; ++j) {
        const float x = kw[o * CC + c0 + j];
        const unsigned short h = bf16_rn(x);
        kwB_hi[base + j] = h;
        kwB_lo[base + j] = bf16_rn(x - bf16_f(h));
    }
}

// ---------------------------------------------------------------------------
// P1: qp projection. MEASUREMENT: nrep, c-loop rotated by rep.
// ---------------------------------------------------------------------------
__global__ void qproj_kernel(const float* __restrict__ q,
                             const float* __restrict__ qw,
                             const float* __restrict__ qb,
                             unsigned short* __restrict__ qp_il,
                             int nrep) {
    __shared__ float qrow[CC];
    const int bq = blockIdx.x;          // b*300 + qi
    const int h  = threadIdx.x;
    qrow[h] = q[bq * CC + h];
    __syncthreads();
    const float* wr = qw + h * CC;
    for (int rep = 0; rep < nrep; ++rep) {
        float acc = qb[h];
        #pragma unroll 4
        for (int ci = 0; ci < 64; ++ci) {
            const int c = ((ci + rep) & 63) << 2;
            float4 w = *reinterpret_cast<const float4*>(wr + c);
            float4 x = *reinterpret_cast<const float4*>(&qrow[c]);
            acc += w.x * x.x + w.y * x.y + w.z * x.z + w.w * x.w;
        }
        acc *= NORM_FACT;
        const unsigned short hi = bf16_rn(acc);
        const size_t base = ((size_t)bq * NH + (h >> 5)) * 64 + (h & 31);
        qp_il[base]      = hi;
        qp_il[base + 32] = bf16_rn(acc - bf16_f(hi));
    }
}

// ---------------------------------------------------------------------------
// P2: kproj, LDS k-staging. MEASUREMENT: nrep; re-stage per rep between
// barriers; ks-loop rotated by rep.
// ---------------------------------------------------------------------------
__global__ __launch_bounds__(256)
void kproj_kernel(const float* __restrict__ kin,
                  const unsigned short* __restrict__ kwB_hi,
                  const unsigned short* __restrict__ kwB_lo,
                  const float* __restrict__ kb,
                  unsigned short* __restrict__ kp_il,
                  int nrep) {
    __shared__ float kf[CC][17];
    const int wid = threadIdx.x >> 6, l = threadIdx.x & 63;
    const int bu  = blockIdx.x;                   // 0..2499
    const int hwt = bu % NT;
    const int b   = bu / NT;
    const int ot4 = wid;
    const int jb  = (l >> 4) * 8;
    const int col = l & 15;

    for (int rep = 0; rep < nrep; ++rep) {
        {   // stage
            const int tid = threadIdx.x;
            const float* kb0 = kin + (size_t)b * CC * HWN + hwt * 16;
            #pragma unroll
            for (int iter = 0; iter < 4; ++iter) {
                const int c   = iter * 64 + (tid >> 2);
                const int cl  = (tid & 3) * 4;
                const float4 v = *reinterpret_cast<const float4*>(
                    kb0 + (size_t)c * HWN + cl);
                kf[c][cl]     = v.x;
                kf[c][cl + 1] = v.y;
                kf[c][cl + 2] = v.z;
                kf[c][cl + 3] = v.w;
            }
        }
        __syncthreads();

        f32x4_t acc[4];
        #pragma unroll
        for (int t = 0; t < 4; ++t) {
            const float bias = kb[(ot4 * 4 + t) * 16 + col];
            acc[t] = {bias, bias, bias, bias};
        }

        #pragma unroll 2
        for (int ksi = 0; ksi < 8; ++ksi) {
            const int ks = (ksi + rep) & 7;
            FragU a_hi, a_lo;
            #pragma unroll
            for (int tt = 0; tt < 4; ++tt) {
                const int c = ks * 32 + jb + 2 * tt;
                const float x0 = kf[c][col];
                const float x1 = kf[c + 1][col];
                const unsigned short h0 = bf16_rn(x0), h1 = bf16_rn(x1);
                const unsigned short g0 = bf16_rn(x0 - bf16_f(h0));
                const unsigned short g1 = bf16_rn(x1 - bf16_f(h1));
                a_hi.u[tt] = (uint32_t)h0 | ((uint32_t)h1 << 16);
                a_lo.u[tt] = (uint32_t)g0 | ((uint32_t)g1 << 16);
            }
            #pragma unroll
            for (int t = 0; t < 4; ++t) {
                const int ot = ot4 * 4 + t;
                const size_t fb = ((size_t)(ot * 8 + ks) * 64 + l) * 8;
                const short8_t bh = *reinterpret_cast<const short8_t*>(kwB_hi + fb);
                const short8_t bl = *reinterpret_cast<const short8_t*>(kwB_lo + fb);
                acc[t] = __builtin_amdgcn_mfma_f32_16x16x32_bf16(a_hi.v, bh, acc[t], 0, 0, 0);
                acc[t] = __builtin_amdgcn_mfma_f32_16x16x32_bf16(a_hi.v, bl, acc[t], 0, 0, 0);
                acc[t] = __builtin_amdgcn_mfma_f32_16x16x32_bf16(a_lo.v, bh, acc[t], 0, 0, 0);
            }
        }

        #pragma unroll
        for (int t = 0; t < 4; ++t) {
            const int o = (ot4 * 4 + t) * 16 + col;
            const int n = o >> 5, osub = o & 31;
            #pragma unroll
            for (int r = 0; r < 4; ++r) {
                const int hwrow = hwt * 16 + (l >> 4) * 4 + r;
                const size_t base = ((size_t)(b * HWN + hwrow) * NH + n) * 64 + osub;
                const float v = acc[t][r];
                const unsigned short h = bf16_rn(v);
                kp_il[base]      = h;
                kp_il[base + 32] = bf16_rn(v - bf16_f(h));
            }
        }
        __syncthreads();   // before next rep's restage
    }
}

// ---------------------------------------------------------------------------
// P3: stats, persistent-kp. MEASUREMENT: nrep, qt-loop rotated by rep.
// ---------------------------------------------------------------------------
__global__ __launch_bounds__(256)
void attn_stats_kernel(const unsigned short* __restrict__ qp_il,
                       const unsigned short* __restrict__ kp_il,
                       const int* __restrict__ mask,
                       float* __restrict__ partials,
                       int nrep) {
    const int wid = threadIdx.x >> 6, l = threadIdx.x & 63;
    const int wu = blockIdx.x * 4 + wid;          // 8000
    const int qh = wu & 1;
    int tmp = wu >> 1;
    const int ch = tmp % NCHUNK; tmp /= NCHUNK;
    const int n = tmp & 7;
    const int b = tmp >> 3;

    short8_t ah[TPC], al[TPC];
    float mf[TPC][4];
    #pragma unroll
    for (int t = 0; t < TPC; ++t) {
        const int tile = ch * TPC + t;
        const int hwr = tile * 16 + (l & 15);
        const size_t abase = ((size_t)(b * HWN + hwr) * NH + n) * 64 + (l >> 4) * 8;
        ah[t] = *reinterpret_cast<const short8_t*>(kp_il + abase);
        al[t] = *reinterpret_cast<const short8_t*>(kp_il + abase + 32);
        const int hw4 = tile * 16 + (l >> 4) * 4;
        const i32x4_t mv = *reinterpret_cast<const i32x4_t*>(mask + b * HWN + hw4);
        mf[t][0] = mv.x ? 0.f : 1.f;
        mf[t][1] = mv.y ? 0.f : 1.f;
        mf[t][2] = mv.z ? 0.f : 1.f;
        mf[t][3] = mv.w ? 0.f : 1.f;
    }

    const int qt0 = qh * 10;
    const int span = qh ? (MT - 10) : 10;
    for (int rep = 0; rep < nrep; ++rep) {
        const int rr = rep % span;
        for (int qti = 0; qti < span; ++qti) {
            int qte = qti + rr; if (qte >= span) qte -= span;
            const int qt = qt0 + qte;
            const int qa = qt * 16 + (l & 15);
            const int qcl = qa < QQ ? qa : QQ - 1;
            const size_t bbase = ((size_t)(b * QQ + qcl) * NH + n) * 64 + (l >> 4) * 8;
            const short8_t bh = *reinterpret_cast<const short8_t*>(qp_il + bbase);
            const short8_t bl = *reinterpret_cast<const short8_t*>(qp_il + bbase + 32);

            float a = 0.f;
            #pragma unroll
            for (int t = 0; t < TPC; ++t) {
                f32x4_t c = {0.f, 0.f, 0.f, 0.f};
                c = __builtin_amdgcn_mfma_f32_16x16x32_bf16(ah[t], bh, c, 0, 0, 0);
                c = __builtin_amdgcn_mfma_f32_16x16x32_bf16(ah[t], bl, c, 0, 0, 0);
                c = __builtin_amdgcn_mfma_f32_16x16x32_bf16(al[t], bh, c, 0, 0, 0);
                a += __expf(c[0]) * mf[t][0] + __expf(c[1]) * mf[t][1]
                   + __expf(c[2]) * mf[t][2] + __expf(c[3]) * mf[t][3];
            }
            a += __shfl_xor(a, 16, 64);
            a += __shfl_xor(a, 32, 64);
            if (l < 16) {
                const int qr = qt * 16 + l;
                if (qr < QQ)
                    partials[(((size_t)b * QQ + qr) * NH + n) * NCHUNK + ch] = a;
            }
        }
    }
}

// ---------------------------------------------------------------------------
// P4: invS[b,q] = 1 / sum over (n,ch) of partials
// ---------------------------------------------------------------------------
__global__ void invsum_kernel(const float* __restrict__ partials,
                              float* __restrict__ invS) {
    const int row = blockIdx.x;    // 1200
    const int l = threadIdx.x;     // 64
    float s = 0.f;
    const float* p = partials + (size_t)row * (NH * NCHUNK);
    for (int i = l; i < NH * NCHUNK; i += 64) s += p[i];
    #pragma unroll
    for (int m = 1; m < 64; m <<= 1) s += __shfl_xor(s, m, 64);
    if (l == 0) invS[row] = 1.0f / s;
}

// ---------------------------------------------------------------------------
// P5: out, persistent-kp. MEASUREMENT: nrep, qt-loop rotated by rep.
// ---------------------------------------------------------------------------
__global__ __launch_bounds__(256)
void attn_out_kernel(const unsigned short* __restrict__ qp_il,
                     const unsigned short* __restrict__ kp_il,
                     const int* __restrict__ mask,
                     const float* __restrict__ invS,
                     float* __restrict__ out,
                     int nrep) {
    const int wid = threadIdx.x >> 6, l = threadIdx.x & 63;
    const int wu = blockIdx.x * 4 + wid;          // 8000
    const int qh = wu & 1;
    int tmp = wu >> 1;
    const int ch = tmp % NCHUNK; tmp /= NCHUNK;
    const int n = tmp & 7;
    const int b = tmp >> 3;

    short8_t ah[TPC], al[TPC];
    float mf[TPC][4];
    int hw4v[TPC];
    #pragma unroll
    for (int t = 0; t < TPC; ++t) {
        const int tile = ch * TPC + t;
        const int hwr = tile * 16 + (l & 15);
        const size_t abase = ((size_t)(b * HWN + hwr) * NH + n) * 64 + (l >> 4) * 8;
        ah[t] = *reinterpret_cast<const short8_t*>(kp_il + abase);
        al[t] = *reinterpret_cast<const short8_t*>(kp_il + abase + 32);
        const int hw4 = tile * 16 + (l >> 4) * 4;
        hw4v[t] = hw4;
        const i32x4_t mv = *reinterpret_cast<const i32x4_t*>(mask + b * HWN + hw4);
        mf[t][0] = mv.x ? 0.f : 1.f;
        mf[t][1] = mv.y ? 0.f : 1.f;
        mf[t][2] = mv.z ? 0.f : 1.f;
        mf[t][3] = mv.w ? 0.f : 1.f;
    }

    const int qt0 = qh * 10;
    const int span = qh ? (MT - 10) : 10;
    for (int rep = 0; rep < nrep; ++rep) {
        const int rr = rep % span;
        for (int qti = 0; qti < span; ++qti) {
            int qte = qti + rr; if (qte >= span) qte -= span;
            const int qt = qt0 + qte;
            const int qa = qt * 16 + (l & 15);
            const int qcl = qa < QQ ? qa : QQ - 1;
            const bool qok = qa < QQ;
            const size_t bbase = ((size_t)(b * QQ + qcl) * NH + n) * 64 + (l >> 4) * 8;
            const short8_t bh = *reinterpret_cast<const short8_t*>(qp_il + bbase);
            const short8_t bl = *reinterpret_cast<const short8_t*>(qp_il + bbase + 32);
            const float is = invS[b * QQ + qcl];
            float* const obase = out + (((size_t)b * QQ + qcl) * NH + n) * HWN;

            #pragma unroll
            for (int t = 0; t < TPC; ++t) {
                f32x4_t c = {0.f, 0.f, 0.f, 0.f};
                c = __builtin_amdgcn_mfma_f32_16x16x32_bf16(ah[t], bh, c, 0, 0, 0);
                c = __builtin_amdgcn_mfma_f32_16x16x32_bf16(ah[t], bl, c, 0, 0, 0);
                c = __builtin_amdgcn_mfma_f32_16x16x32_bf16(al[t], bh, c, 0, 0, 0);
                f32x4_t rv;
                rv[0] = __expf(c[0]) * is * mf[t][0];
                rv[1] = __expf(c[1]) * is * mf[t][1];
                rv[2] = __expf(c[2]) * is * mf[t][2];
                rv[3] = __expf(c[3]) * is * mf[t][3];
                if (qok)
                    __builtin_nontemporal_store(rv,
                        reinterpret_cast<f32x4_t*>(obase + hw4v[t]));
            }
        }
    }
}

// ---------------------------------------------------------------------------
extern "C" void kernel_launch(void* const* d_in, const int* in_sizes, int n_in,
                              void* d_out, int out_size, void* d_ws, size_t ws_size,
                              hipStream_t stream) {
    const float* q    = (const float*)d_in[0];
    const float* k    = (const float*)d_in[1];
    const int*   mask = (const int*)d_in[2];
    const float* qw   = (const float*)d_in[3];
    const float* qb   = (const float*)d_in[4];
    const float* kw   = (const float*)d_in[5];
    const float* kb   = (const float*)d_in[6];
    float* out = (float*)d_out;

    // ws layout (bytes) — total 42,193,600 B (proven footprint):
    char* wsb = (char*)d_ws;
    unsigned short* kp_il = (unsigned short*)wsb;                    // 40.96 MB
    unsigned short* qp_il = (unsigned short*)(wsb + 40960000);       // 1.2288 MB
    float* invS           = (float*)(wsb + 40960000 + 1228800);      // 4.8 KB

    // scratch parked in d_out (stream-ordered; P5 overwrites all of d_out):
    unsigned short* kwB_hi = (unsigned short*)d_out;
    unsigned short* kwB_lo = kwB_hi + 65536;
    float* partials = (float*)((char*)d_out + (4u << 20));           // 4.8 MB

    // MEASUREMENT ROUND: nrep pushes each kernel above the ~217us fill
    // threshold so all four appear in top-5 with their counters.
    prep_kwB_kernel<<<dim3(16, 8), 64, 0, stream>>>(kw, kwB_hi, kwB_lo);
    qproj_kernel<<<BB * QQ, 256, 0, stream>>>(q, qw, qb, qp_il, /*nrep=*/40);
    kproj_kernel<<<BB * NT, 256, 0, stream>>>(k, kwB_hi, kwB_lo, kb, kp_il, /*nrep=*/10);
    attn_stats_kernel<<<(BB * NH * NCHUNK * 2) / 4, 256, 0, stream>>>(
        qp_il, kp_il, mask, partials, /*nrep=*/10);
    invsum_kernel<<<BB * QQ, 64, 0, stream>>>(partials, invS);
    attn_out_kernel<<<(BB * NH * NCHUNK * 2) / 4, 256, 0, stream>>>(
        qp_il, kp_il, mask, invS, out, /*nrep=*/4);
}

// Round 15
// 224.346 us; speedup vs baseline: 12.3166x; 12.3166x over previous
//
#include <hip/hip_runtime.h>
#include <math.h>

// Problem constants (fixed by the reference)
#define BB 4
#define QQ 300
#define CC 256          // QUERY_DIM / hidden
#define NH 8
#define HD 32           // head dim
#define HWN 10000       // H*W
#define NT 625          // hw tiles of 16
#define NCHUNK 125      // hw chunks per (b,n)
#define TPC 5           // hw tiles per chunk (125*5=625)
#define MT 19           // q tiles of 16
#define NORM_FACT 0.17677669529663687f  // 32^-0.5

typedef __attribute__((ext_vector_type(8))) short short8_t;   // 8 bf16 (4 VGPR)
typedef __attribute__((ext_vector_type(4))) float f32x4_t;    // MFMA C/D
typedef __attribute__((ext_vector_type(4))) int   i32x4_t;

union FragU { uint32_t u[4]; short8_t v; };

__device__ __forceinline__ unsigned short bf16_rn(float x) {
    uint32_t u = __float_as_uint(x);
    return (unsigned short)((u + 0x7fffu + ((u >> 16) & 1u)) >> 16);
}
__device__ __forceinline__ float bf16_f(unsigned short h) {
    return __uint_as_float(((uint32_t)h) << 16);
}

// ---------------------------------------------------------------------------
// P0: pre-pack a [256,256] row-major weight (split bf16) into MFMA B-fragment
// order. Used for BOTH kw and qw.
// ---------------------------------------------------------------------------
__global__ void prep_kwB_kernel(const float* __restrict__ kw,
                                unsigned short* __restrict__ kwB_hi,
                                unsigned short* __restrict__ kwB_lo) {
    const int ot = blockIdx.x, ks = blockIdx.y;    // 16 x 8
    const int l = threadIdx.x;                     // 64
    const int o = ot * 16 + (l & 15);
    const int c0 = ks * 32 + (l >> 4) * 8;
    const size_t base = ((size_t)(ot * 8 + ks) * 64 + l) * 8;
    #pragma unroll
    for (int j = 0; j < 8; ++j) {
        const float x = kw[o * CC + c0 + j];
        const unsigned short h = bf16_rn(x);
        kwB_hi[base + j] = h;
        kwB_lo[base + j] = bf16_rn(x - bf16_f(h));
    }
}

// ---------------------------------------------------------------------------
// P1 v2: qproj via MFMA (round-14 counters: old qproj was 47us latency-bound
// on 1KB-strided qw row loads). 1200 rows = 75 tiles of 16; block = row-tile,
// wave = 4 ot-tiles. A-frags are contiguous 16B/lane q-row reads.
// qp = (q @ qw^T + qb) * NORM_FACT -> interleaved split-bf16.
// ---------------------------------------------------------------------------
__global__ __launch_bounds__(256)
void qproj_kernel(const float* __restrict__ qin,
                  const unsigned short* __restrict__ qwB_hi,
                  const unsigned short* __restrict__ qwB_lo,
                  const float* __restrict__ qb,
                  unsigned short* __restrict__ qp_il) {
    const int wid = threadIdx.x >> 6, l = threadIdx.x & 63;
    const int rt = blockIdx.x;                    // 0..74 (row tile over 1200)
    const int ot4 = wid;
    const int jb = (l >> 4) * 8;
    const int col = l & 15;

    // A-frags: q rows -> split bf16, 8 ksteps, persistent
    FragU a_hi[8], a_lo[8];
    const float* abase = qin + ((size_t)rt * 16 + col) * CC;
    #pragma unroll
    for (int ks = 0; ks < 8; ++ks) {
        #pragma unroll
        for (int tt = 0; tt < 4; ++tt) {
            const int c = ks * 32 + jb + 2 * tt;
            const float x0 = abase[c];
            const float x1 = abase[c + 1];
            const unsigned short h0 = bf16_rn(x0), h1 = bf16_rn(x1);
            const unsigned short g0 = bf16_rn(x0 - bf16_f(h0));
            const unsigned short g1 = bf16_rn(x1 - bf16_f(h1));
            a_hi[ks].u[tt] = (uint32_t)h0 | ((uint32_t)h1 << 16);
            a_lo[ks].u[tt] = (uint32_t)g0 | ((uint32_t)g1 << 16);
        }
    }

    #pragma unroll 1
    for (int t = 0; t < 4; ++t) {
        const int ot = ot4 * 4 + t;
        f32x4_t c = {0.f, 0.f, 0.f, 0.f};
        #pragma unroll
        for (int ks = 0; ks < 8; ++ks) {
            const size_t fb = ((size_t)(ot * 8 + ks) * 64 + l) * 8;
            const short8_t bh = *reinterpret_cast<const short8_t*>(qwB_hi + fb);
            const short8_t bl = *reinterpret_cast<const short8_t*>(qwB_lo + fb);
            c = __builtin_amdgcn_mfma_f32_16x16x32_bf16(a_hi[ks].v, bh, c, 0, 0, 0);
            c = __builtin_amdgcn_mfma_f32_16x16x32_bf16(a_hi[ks].v, bl, c, 0, 0, 0);
            c = __builtin_amdgcn_mfma_f32_16x16x32_bf16(a_lo[ks].v, bh, c, 0, 0, 0);
        }
        const int o = ot * 16 + col;
        const int n = o >> 5, osub = o & 31;
        const float bias = qb[o];
        #pragma unroll
        for (int r = 0; r < 4; ++r) {
            const int row = rt * 16 + (l >> 4) * 4 + r;   // 0..1199
            const float v = (c[r] + bias) * NORM_FACT;
            const size_t base = ((size_t)row * NH + n) * 64 + osub;
            const unsigned short h = bf16_rn(v);
            qp_il[base]      = h;
            qp_il[base + 32] = bf16_rn(v - bf16_f(h));
        }
    }
}

// ---------------------------------------------------------------------------
// P2: kproj via MFMA with LDS k-staging (round-13 version, nrep removed).
// ---------------------------------------------------------------------------
__global__ __launch_bounds__(256)
void kproj_kernel(const float* __restrict__ kin,
                  const unsigned short* __restrict__ kwB_hi,
                  const unsigned short* __restrict__ kwB_lo,
                  const float* __restrict__ kb,
                  unsigned short* __restrict__ kp_il) {
    __shared__ float kf[CC][17];
    const int wid = threadIdx.x >> 6, l = threadIdx.x & 63;
    const int bu  = blockIdx.x;                   // 0..2499
    const int hwt = bu % NT;
    const int b   = bu / NT;
    const int ot4 = wid;

    {
        const int tid = threadIdx.x;
        const float* kb0 = kin + (size_t)b * CC * HWN + hwt * 16;
        #pragma unroll
        for (int iter = 0; iter < 4; ++iter) {
            const int c   = iter * 64 + (tid >> 2);
            const int cl  = (tid & 3) * 4;
            const float4 v = *reinterpret_cast<const float4*>(
                kb0 + (size_t)c * HWN + cl);
            kf[c][cl]     = v.x;
            kf[c][cl + 1] = v.y;
            kf[c][cl + 2] = v.z;
            kf[c][cl + 3] = v.w;
        }
    }
    __syncthreads();

    const int jb  = (l >> 4) * 8;
    const int col = l & 15;

    f32x4_t acc[4];
    #pragma unroll
    for (int t = 0; t < 4; ++t) {
        const float bias = kb[(ot4 * 4 + t) * 16 + col];
        acc[t] = {bias, bias, bias, bias};
    }

    #pragma unroll 2
    for (int ks = 0; ks < 8; ++ks) {
        FragU a_hi, a_lo;
        #pragma unroll
        for (int tt = 0; tt < 4; ++tt) {
            const int c = ks * 32 + jb + 2 * tt;
            const float x0 = kf[c][col];
            const float x1 = kf[c + 1][col];
            const unsigned short h0 = bf16_rn(x0), h1 = bf16_rn(x1);
            const unsigned short g0 = bf16_rn(x0 - bf16_f(h0));
            const unsigned short g1 = bf16_rn(x1 - bf16_f(h1));
            a_hi.u[tt] = (uint32_t)h0 | ((uint32_t)h1 << 16);
            a_lo.u[tt] = (uint32_t)g0 | ((uint32_t)g1 << 16);
        }
        #pragma unroll
        for (int t = 0; t < 4; ++t) {
            const int ot = ot4 * 4 + t;
            const size_t fb = ((size_t)(ot * 8 + ks) * 64 + l) * 8;
            const short8_t bh = *reinterpret_cast<const short8_t*>(kwB_hi + fb);
            const short8_t bl = *reinterpret_cast<const short8_t*>(kwB_lo + fb);
            acc[t] = __builtin_amdgcn_mfma_f32_16x16x32_bf16(a_hi.v, bh, acc[t], 0, 0, 0);
            acc[t] = __builtin_amdgcn_mfma_f32_16x16x32_bf16(a_hi.v, bl, acc[t], 0, 0, 0);
            acc[t] = __builtin_amdgcn_mfma_f32_16x16x32_bf16(a_lo.v, bh, acc[t], 0, 0, 0);
        }
    }

    #pragma unroll
    for (int t = 0; t < 4; ++t) {
        const int o = (ot4 * 4 + t) * 16 + col;
        const int n = o >> 5, osub = o & 31;
        #pragma unroll
        for (int r = 0; r < 4; ++r) {
            const int hwrow = hwt * 16 + (l >> 4) * 4 + r;
            const size_t base = ((size_t)(b * HWN + hwrow) * NH + n) * 64 + osub;
            const float v = acc[t][r];
            const unsigned short h = bf16_rn(v);
            kp_il[base]      = h;
            kp_il[base + 32] = bf16_rn(v - bf16_f(h));
        }
    }
}

// ---------------------------------------------------------------------------
// P3: softmax denominator partials — persistent-kp / stream-qp, qh split.
// ---------------------------------------------------------------------------
__global__ __launch_bounds__(256)
void attn_stats_kernel(const unsigned short* __restrict__ qp_il,
                       const unsigned short* __restrict__ kp_il,
                       const int* __restrict__ mask,
                       float* __restrict__ partials) {
    const int wid = threadIdx.x >> 6, l = threadIdx.x & 63;
    const int wu = blockIdx.x * 4 + wid;          // 8000
    const int qh = wu & 1;
    int tmp = wu >> 1;
    const int ch = tmp % NCHUNK; tmp /= NCHUNK;
    const int n = tmp & 7;
    const int b = tmp >> 3;

    short8_t ah[TPC], al[TPC];
    float mf[TPC][4];
    #pragma unroll
    for (int t = 0; t < TPC; ++t) {
        const int tile = ch * TPC + t;
        const int hwr = tile * 16 + (l & 15);
        const size_t abase = ((size_t)(b * HWN + hwr) * NH + n) * 64 + (l >> 4) * 8;
        ah[t] = *reinterpret_cast<const short8_t*>(kp_il + abase);
        al[t] = *reinterpret_cast<const short8_t*>(kp_il + abase + 32);
        const int hw4 = tile * 16 + (l >> 4) * 4;
        const i32x4_t mv = *reinterpret_cast<const i32x4_t*>(mask + b * HWN + hw4);
        mf[t][0] = mv.x ? 0.f : 1.f;
        mf[t][1] = mv.y ? 0.f : 1.f;
        mf[t][2] = mv.z ? 0.f : 1.f;
        mf[t][3] = mv.w ? 0.f : 1.f;
    }

    const int qt0 = qh * 10;
    const int qt1 = qh ? MT : 10;
    #pragma unroll 2
    for (int qt = qt0; qt < qt1; ++qt) {
        const int qa = qt * 16 + (l & 15);
        const int qcl = qa < QQ ? qa : QQ - 1;
        const size_t bbase = ((size_t)(b * QQ + qcl) * NH + n) * 64 + (l >> 4) * 8;
        const short8_t bh = *reinterpret_cast<const short8_t*>(qp_il + bbase);
        const short8_t bl = *reinterpret_cast<const short8_t*>(qp_il + bbase + 32);

        float a = 0.f;
        #pragma unroll
        for (int t = 0; t < TPC; ++t) {
            f32x4_t c = {0.f, 0.f, 0.f, 0.f};
            c = __builtin_amdgcn_mfma_f32_16x16x32_bf16(ah[t], bh, c, 0, 0, 0);
            c = __builtin_amdgcn_mfma_f32_16x16x32_bf16(ah[t], bl, c, 0, 0, 0);
            c = __builtin_amdgcn_mfma_f32_16x16x32_bf16(al[t], bh, c, 0, 0, 0);
            a += __expf(c[0]) * mf[t][0] + __expf(c[1]) * mf[t][1]
               + __expf(c[2]) * mf[t][2] + __expf(c[3]) * mf[t][3];
        }
        a += __shfl_xor(a, 16, 64);
        a += __shfl_xor(a, 32, 64);
        if (l < 16) {
            const int qr = qt * 16 + l;
            if (qr < QQ)
                partials[(((size_t)b * QQ + qr) * NH + n) * NCHUNK + ch] = a;
        }
    }
}

// ---------------------------------------------------------------------------
// P4: invS[b,q] = 1 / sum over (n,ch) of partials  (1000 values per row)
// ---------------------------------------------------------------------------
__global__ void invsum_kernel(const float* __restrict__ partials,
                              float* __restrict__ invS) {
    const int row = blockIdx.x;    // 1200
    const int l = threadIdx.x;     // 64
    float s = 0.f;
    const float* p = partials + (size_t)row * (NH * NCHUNK);
    for (int i = l; i < NH * NCHUNK; i += 64) s += p[i];
    #pragma unroll
    for (int m = 1; m < 64; m <<= 1) s += __shfl_xor(s, m, 64);
    if (l == 0) invS[row] = 1.0f / s;
}

// ---------------------------------------------------------------------------
// P5: out = exp(logit)*invS*mfac — persistent-kp / stream-qp, qh split.
// PLAIN stores (NT removed): let L2 assemble fully-dirty 64B lines and
// stream at fill-rate (round-14: NT path ran at only ~2.2 TB/s).
// ---------------------------------------------------------------------------
__global__ __launch_bounds__(256)
void attn_out_kernel(const unsigned short* __restrict__ qp_il,
                     const unsigned short* __restrict__ kp_il,
                     const int* __restrict__ mask,
                     const float* __restrict__ invS,
                     float* __restrict__ out) {
    const int wid = threadIdx.x >> 6, l = threadIdx.x & 63;
    const int wu = blockIdx.x * 4 + wid;          // 8000
    const int qh = wu & 1;
    int tmp = wu >> 1;
    const int ch = tmp % NCHUNK; tmp /= NCHUNK;
    const int n = tmp & 7;
    const int b = tmp >> 3;

    short8_t ah[TPC], al[TPC];
    float mf[TPC][4];
    int hw4v[TPC];
    #pragma unroll
    for (int t = 0; t < TPC; ++t) {
        const int tile = ch * TPC + t;
        const int hwr = tile * 16 + (l & 15);
        const size_t abase = ((size_t)(b * HWN + hwr) * NH + n) * 64 + (l >> 4) * 8;
        ah[t] = *reinterpret_cast<const short8_t*>(kp_il + abase);
        al[t] = *reinterpret_cast<const short8_t*>(kp_il + abase + 32);
        const int hw4 = tile * 16 + (l >> 4) * 4;
        hw4v[t] = hw4;
        const i32x4_t mv = *reinterpret_cast<const i32x4_t*>(mask + b * HWN + hw4);
        mf[t][0] = mv.x ? 0.f : 1.f;
        mf[t][1] = mv.y ? 0.f : 1.f;
        mf[t][2] = mv.z ? 0.f : 1.f;
        mf[t][3] = mv.w ? 0.f : 1.f;
    }

    const int qt0 = qh * 10;
    const int qt1 = qh ? MT : 10;
    #pragma unroll 2
    for (int qt = qt0; qt < qt1; ++qt) {
        const int qa = qt * 16 + (l & 15);
        const int qcl = qa < QQ ? qa : QQ - 1;
        const bool qok = qa < QQ;
        const size_t bbase = ((size_t)(b * QQ + qcl) * NH + n) * 64 + (l >> 4) * 8;
        const short8_t bh = *reinterpret_cast<const short8_t*>(qp_il + bbase);
        const short8_t bl = *reinterpret_cast<const short8_t*>(qp_il + bbase + 32);
        const float is = invS[b * QQ + qcl];
        float* const obase = out + (((size_t)b * QQ + qcl) * NH + n) * HWN;

        #pragma unroll
        for (int t = 0; t < TPC; ++t) {
            f32x4_t c = {0.f, 0.f, 0.f, 0.f};
            c = __builtin_amdgcn_mfma_f32_16x16x32_bf16(ah[t], bh, c, 0, 0, 0);
            c = __builtin_amdgcn_mfma_f32_16x16x32_bf16(ah[t], bl, c, 0, 0, 0);
            c = __builtin_amdgcn_mfma_f32_16x16x32_bf16(al[t], bh, c, 0, 0, 0);
            f32x4_t rv;
            rv[0] = __expf(c[0]) * is * mf[t][0];
            rv[1] = __expf(c[1]) * is * mf[t][1];
            rv[2] = __expf(c[2]) * is * mf[t][2];
            rv[3] = __expf(c[3]) * is * mf[t][3];
            if (qok)
                *reinterpret_cast<f32x4_t*>(obase + hw4v[t]) = rv;
        }
    }
}

// ---------------------------------------------------------------------------
extern "C" void kernel_launch(void* const* d_in, const int* in_sizes, int n_in,
                              void* d_out, int out_size, void* d_ws, size_t ws_size,
                              hipStream_t stream) {
    const float* q    = (const float*)d_in[0];
    const float* k    = (const float*)d_in[1];
    const int*   mask = (const int*)d_in[2];
    const float* qw   = (const float*)d_in[3];
    const float* qb   = (const float*)d_in[4];
    const float* kw   = (const float*)d_in[5];
    const float* kb   = (const float*)d_in[6];
    float* out = (float*)d_out;

    // ws layout (bytes) — total 42,193,600 B (proven footprint):
    char* wsb = (char*)d_ws;
    unsigned short* kp_il = (unsigned short*)wsb;                    // 40.96 MB
    unsigned short* qp_il = (unsigned short*)(wsb + 40960000);       // 1.2288 MB
    float* invS           = (float*)(wsb + 40960000 + 1228800);      // 4.8 KB

    // scratch parked in d_out (stream-ordered; P5 overwrites all of d_out):
    //   kwB/qwB fragment planes (4 x 128KB), partials at byte 4MB
    unsigned short* kwB_hi = (unsigned short*)d_out;
    unsigned short* kwB_lo = kwB_hi + 65536;
    unsigned short* qwB_hi = kwB_hi + 131072;
    unsigned short* qwB_lo = kwB_hi + 196608;
    float* partials = (float*)((char*)d_out + (4u << 20));           // 4.8 MB

    prep_kwB_kernel<<<dim3(16, 8), 64, 0, stream>>>(kw, kwB_hi, kwB_lo);
    prep_kwB_kernel<<<dim3(16, 8), 64, 0, stream>>>(qw, qwB_hi, qwB_lo);
    qproj_kernel<<<75, 256, 0, stream>>>(q, qwB_hi, qwB_lo, qb, qp_il);
    kproj_kernel<<<BB * NT, 256, 0, stream>>>(k, kwB_hi, kwB_lo, kb, kp_il);
    attn_stats_kernel<<<(BB * NH * NCHUNK * 2) / 4, 256, 0, stream>>>(
        qp_il, kp_il, mask, partials);
    invsum_kernel<<<BB * QQ, 64, 0, stream>>>(partials, invS);
    attn_out_kernel<<<(BB * NH * NCHUNK * 2) / 4, 256, 0, stream>>>(
        qp_il, kp_il, mask, invS, out);
}

// Round 16
// 219.203 us; speedup vs baseline: 12.6056x; 1.0235x over previous
//
#include <hip/hip_runtime.h>
#include <math.h>

// Problem constants (fixed by the reference)
#define BB 4
#define QQ 300
#define CC 256          // QUERY_DIM / hidden
#define NH 8
#define HD 32           // head dim
#define HWN 10000       // H*W
#define NT 625          // hw tiles of 16
#define NCHUNK 125      // hw chunks
#define TPC 5           // hw tiles per chunk (125*5=625)
#define QCH 4           // q chunks (out pass)
#define NQT 5           // q tiles per chunk (out pass)
#define MT 19           // q tiles of 16
#define NORM_FACT 0.17677669529663687f  // 32^-0.5

typedef __attribute__((ext_vector_type(8))) short short8_t;   // 8 bf16 (4 VGPR)
typedef __attribute__((ext_vector_type(4))) float f32x4_t;    // MFMA C/D
typedef __attribute__((ext_vector_type(4))) int   i32x4_t;

union FragU { uint32_t u[4]; short8_t v; };

__device__ __forceinline__ unsigned short bf16_rn(float x) {
    uint32_t u = __float_as_uint(x);
    return (unsigned short)((u + 0x7fffu + ((u >> 16) & 1u)) >> 16);
}
__device__ __forceinline__ float bf16_f(unsigned short h) {
    return __uint_as_float(((uint32_t)h) << 16);
}

// ---------------------------------------------------------------------------
// P0: pre-pack a [256,256] row-major weight (split bf16) into MFMA B-fragment
// order. Used for BOTH kw and qw.
// ---------------------------------------------------------------------------
__global__ void prep_kwB_kernel(const float* __restrict__ kw,
                                unsigned short* __restrict__ kwB_hi,
                                unsigned short* __restrict__ kwB_lo) {
    const int ot = blockIdx.x, ks = blockIdx.y;    // 16 x 8
    const int l = threadIdx.x;                     // 64
    const int o = ot * 16 + (l & 15);
    const int c0 = ks * 32 + (l >> 4) * 8;
    const size_t base = ((size_t)(ot * 8 + ks) * 64 + l) * 8;
    #pragma unroll
    for (int j = 0; j < 8; ++j) {
        const float x = kw[o * CC + c0 + j];
        const unsigned short h = bf16_rn(x);
        kwB_hi[base + j] = h;
        kwB_lo[base + j] = bf16_rn(x - bf16_f(h));
    }
}

// ---------------------------------------------------------------------------
// P1: qproj via MFMA (R15 version, kept).
// ---------------------------------------------------------------------------
__global__ __launch_bounds__(256)
void qproj_kernel(const float* __restrict__ qin,
                  const unsigned short* __restrict__ qwB_hi,
                  const unsigned short* __restrict__ qwB_lo,
                  const float* __restrict__ qb,
                  unsigned short* __restrict__ qp_il) {
    const int wid = threadIdx.x >> 6, l = threadIdx.x & 63;
    const int rt = blockIdx.x;                    // 0..74
    const int ot4 = wid;
    const int jb = (l >> 4) * 8;
    const int col = l & 15;

    FragU a_hi[8], a_lo[8];
    const float* abase = qin + ((size_t)rt * 16 + col) * CC;
    #pragma unroll
    for (int ks = 0; ks < 8; ++ks) {
        #pragma unroll
        for (int tt = 0; tt < 4; ++tt) {
            const int c = ks * 32 + jb + 2 * tt;
            const float x0 = abase[c];
            const float x1 = abase[c + 1];
            const unsigned short h0 = bf16_rn(x0), h1 = bf16_rn(x1);
            const unsigned short g0 = bf16_rn(x0 - bf16_f(h0));
            const unsigned short g1 = bf16_rn(x1 - bf16_f(h1));
            a_hi[ks].u[tt] = (uint32_t)h0 | ((uint32_t)h1 << 16);
            a_lo[ks].u[tt] = (uint32_t)g0 | ((uint32_t)g1 << 16);
        }
    }

    #pragma unroll 1
    for (int t = 0; t < 4; ++t) {
        const int ot = ot4 * 4 + t;
        f32x4_t c = {0.f, 0.f, 0.f, 0.f};
        #pragma unroll
        for (int ks = 0; ks < 8; ++ks) {
            const size_t fb = ((size_t)(ot * 8 + ks) * 64 + l) * 8;
            const short8_t bh = *reinterpret_cast<const short8_t*>(qwB_hi + fb);
            const short8_t bl = *reinterpret_cast<const short8_t*>(qwB_lo + fb);
            c = __builtin_amdgcn_mfma_f32_16x16x32_bf16(a_hi[ks].v, bh, c, 0, 0, 0);
            c = __builtin_amdgcn_mfma_f32_16x16x32_bf16(a_hi[ks].v, bl, c, 0, 0, 0);
            c = __builtin_amdgcn_mfma_f32_16x16x32_bf16(a_lo[ks].v, bh, c, 0, 0, 0);
        }
        const int o = ot * 16 + col;
        const int n = o >> 5, osub = o & 31;
        const float bias = qb[o];
        #pragma unroll
        for (int r = 0; r < 4; ++r) {
            const int row = rt * 16 + (l >> 4) * 4 + r;   // 0..1199
            const float v = (c[r] + bias) * NORM_FACT;
            const size_t base = ((size_t)row * NH + n) * 64 + osub;
            const unsigned short h = bf16_rn(v);
            qp_il[base]      = h;
            qp_il[base + 32] = bf16_rn(v - bf16_f(h));
        }
    }
}

// ---------------------------------------------------------------------------
// P2: kproj via MFMA with LDS k-staging (R13 version, kept).
// ---------------------------------------------------------------------------
__global__ __launch_bounds__(256)
void kproj_kernel(const float* __restrict__ kin,
                  const unsigned short* __restrict__ kwB_hi,
                  const unsigned short* __restrict__ kwB_lo,
                  const float* __restrict__ kb,
                  unsigned short* __restrict__ kp_il) {
    __shared__ float kf[CC][17];
    const int wid = threadIdx.x >> 6, l = threadIdx.x & 63;
    const int bu  = blockIdx.x;                   // 0..2499
    const int hwt = bu % NT;
    const int b   = bu / NT;
    const int ot4 = wid;

    {
        const int tid = threadIdx.x;
        const float* kb0 = kin + (size_t)b * CC * HWN + hwt * 16;
        #pragma unroll
        for (int iter = 0; iter < 4; ++iter) {
            const int c   = iter * 64 + (tid >> 2);
            const int cl  = (tid & 3) * 4;
            const float4 v = *reinterpret_cast<const float4*>(
                kb0 + (size_t)c * HWN + cl);
            kf[c][cl]     = v.x;
            kf[c][cl + 1] = v.y;
            kf[c][cl + 2] = v.z;
            kf[c][cl + 3] = v.w;
        }
    }
    __syncthreads();

    const int jb  = (l >> 4) * 8;
    const int col = l & 15;

    f32x4_t acc[4];
    #pragma unroll
    for (int t = 0; t < 4; ++t) {
        const float bias = kb[(ot4 * 4 + t) * 16 + col];
        acc[t] = {bias, bias, bias, bias};
    }

    #pragma unroll 2
    for (int ks = 0; ks < 8; ++ks) {
        FragU a_hi, a_lo;
        #pragma unroll
        for (int tt = 0; tt < 4; ++tt) {
            const int c = ks * 32 + jb + 2 * tt;
            const float x0 = kf[c][col];
            const float x1 = kf[c + 1][col];
            const unsigned short h0 = bf16_rn(x0), h1 = bf16_rn(x1);
            const unsigned short g0 = bf16_rn(x0 - bf16_f(h0));
            const unsigned short g1 = bf16_rn(x1 - bf16_f(h1));
            a_hi.u[tt] = (uint32_t)h0 | ((uint32_t)h1 << 16);
            a_lo.u[tt] = (uint32_t)g0 | ((uint32_t)g1 << 16);
        }
        #pragma unroll
        for (int t = 0; t < 4; ++t) {
            const int ot = ot4 * 4 + t;
            const size_t fb = ((size_t)(ot * 8 + ks) * 64 + l) * 8;
            const short8_t bh = *reinterpret_cast<const short8_t*>(kwB_hi + fb);
            const short8_t bl = *reinterpret_cast<const short8_t*>(kwB_lo + fb);
            acc[t] = __builtin_amdgcn_mfma_f32_16x16x32_bf16(a_hi.v, bh, acc[t], 0, 0, 0);
            acc[t] = __builtin_amdgcn_mfma_f32_16x16x32_bf16(a_hi.v, bl, acc[t], 0, 0, 0);
            acc[t] = __builtin_amdgcn_mfma_f32_16x16x32_bf16(a_lo.v, bh, acc[t], 0, 0, 0);
        }
    }

    #pragma unroll
    for (int t = 0; t < 4; ++t) {
        const int o = (ot4 * 4 + t) * 16 + col;
        const int n = o >> 5, osub = o & 31;
        #pragma unroll
        for (int r = 0; r < 4; ++r) {
            const int hwrow = hwt * 16 + (l >> 4) * 4 + r;
            const size_t base = ((size_t)(b * HWN + hwrow) * NH + n) * 64 + osub;
            const float v = acc[t][r];
            const unsigned short h = bf16_rn(v);
            kp_il[base]      = h;
            kp_il[base + 32] = bf16_rn(v - bf16_f(h));
        }
    }
}

// ---------------------------------------------------------------------------
// P3: stats — persistent-kp / stream-qp, qh split (R13 version, kept).
// ---------------------------------------------------------------------------
__global__ __launch_bounds__(256)
void attn_stats_kernel(const unsigned short* __restrict__ qp_il,
                       const unsigned short* __restrict__ kp_il,
                       const int* __restrict__ mask,
                       float* __restrict__ partials) {
    const int wid = threadIdx.x >> 6, l = threadIdx.x & 63;
    const int wu = blockIdx.x * 4 + wid;          // 8000
    const int qh = wu & 1;
    int tmp = wu >> 1;
    const int ch = tmp % NCHUNK; tmp /= NCHUNK;
    const int n = tmp & 7;
    const int b = tmp >> 3;

    short8_t ah[TPC], al[TPC];
    float mf[TPC][4];
    #pragma unroll
    for (int t = 0; t < TPC; ++t) {
        const int tile = ch * TPC + t;
        const int hwr = tile * 16 + (l & 15);
        const size_t abase = ((size_t)(b * HWN + hwr) * NH + n) * 64 + (l >> 4) * 8;
        ah[t] = *reinterpret_cast<const short8_t*>(kp_il + abase);
        al[t] = *reinterpret_cast<const short8_t*>(kp_il + abase + 32);
        const int hw4 = tile * 16 + (l >> 4) * 4;
        const i32x4_t mv = *reinterpret_cast<const i32x4_t*>(mask + b * HWN + hw4);
        mf[t][0] = mv.x ? 0.f : 1.f;
        mf[t][1] = mv.y ? 0.f : 1.f;
        mf[t][2] = mv.z ? 0.f : 1.f;
        mf[t][3] = mv.w ? 0.f : 1.f;
    }

    const int qt0 = qh * 10;
    const int qt1 = qh ? MT : 10;
    #pragma unroll 2
    for (int qt = qt0; qt < qt1; ++qt) {
        const int qa = qt * 16 + (l & 15);
        const int qcl = qa < QQ ? qa : QQ - 1;
        const size_t bbase = ((size_t)(b * QQ + qcl) * NH + n) * 64 + (l >> 4) * 8;
        const short8_t bh = *reinterpret_cast<const short8_t*>(qp_il + bbase);
        const short8_t bl = *reinterpret_cast<const short8_t*>(qp_il + bbase + 32);

        float a = 0.f;
        #pragma unroll
        for (int t = 0; t < TPC; ++t) {
            f32x4_t c = {0.f, 0.f, 0.f, 0.f};
            c = __builtin_amdgcn_mfma_f32_16x16x32_bf16(ah[t], bh, c, 0, 0, 0);
            c = __builtin_amdgcn_mfma_f32_16x16x32_bf16(ah[t], bl, c, 0, 0, 0);
            c = __builtin_amdgcn_mfma_f32_16x16x32_bf16(al[t], bh, c, 0, 0, 0);
            a += __expf(c[0]) * mf[t][0] + __expf(c[1]) * mf[t][1]
               + __expf(c[2]) * mf[t][2] + __expf(c[3]) * mf[t][3];
        }
        a += __shfl_xor(a, 16, 64);
        a += __shfl_xor(a, 32, 64);
        if (l < 16) {
            const int qr = qt * 16 + l;
            if (qr < QQ)
                partials[(((size_t)b * QQ + qr) * NH + n) * NCHUNK + ch] = a;
        }
    }
}

// ---------------------------------------------------------------------------
// P4: invS[b,q] = 1 / sum over (n,ch) of partials  (1000 values per row)
// ---------------------------------------------------------------------------
__global__ void invsum_kernel(const float* __restrict__ partials,
                              float* __restrict__ invS) {
    const int row = blockIdx.x;    // 1200
    const int l = threadIdx.x;     // 64
    float s = 0.f;
    const float* p = partials + (size_t)row * (NH * NCHUNK);
    for (int i = l; i < NH * NCHUNK; i += 64) s += p[i];
    #pragma unroll
    for (int m = 1; m < 64; m <<= 1) s += __shfl_xor(s, m, 64);
    if (l == 0) invS[row] = 1.0f / s;
}

// ---------------------------------------------------------------------------
// P5: out — REVERTED to the measured-best R10 structure: 5 persistent qp
// B-frags, kp streamed per tile, 16000 waves, NT stores. (R12's
// persistent-kp variant measured ~165us vs this structure's ~105us.)
// ---------------------------------------------------------------------------
__global__ __launch_bounds__(256)
void attn_out_kernel(const unsigned short* __restrict__ qp_il,
                     const unsigned short* __restrict__ kp_il,
                     const int* __restrict__ mask,
                     const float* __restrict__ invS,
                     float* __restrict__ out) {
    const int wid = threadIdx.x >> 6, l = threadIdx.x & 63;
    const int wu = blockIdx.x * 4 + wid;          // 16000
    const int ch = wu % NCHUNK;
    int tmp = wu / NCHUNK;
    const int qc = tmp % QCH; tmp /= QCH;
    const int n = tmp & 7;
    const int b = tmp >> 3;

    short8_t bh[NQT], bl[NQT];
    float isv[NQT];
    float* optr[NQT];
    bool qok[NQT];
    #pragma unroll
    for (int tt = 0; tt < NQT; ++tt) {
        const int qa = (qc * NQT + tt) * 16 + (l & 15);
        const int qcl = qa < QQ ? qa : QQ - 1;
        qok[tt] = qa < QQ;
        const size_t bbase = ((size_t)(b * QQ + qcl) * NH + n) * 64 + (l >> 4) * 8;
        bh[tt] = *reinterpret_cast<const short8_t*>(qp_il + bbase);
        bl[tt] = *reinterpret_cast<const short8_t*>(qp_il + bbase + 32);
        isv[tt] = invS[b * QQ + qcl];
        optr[tt] = out + (((size_t)b * QQ + qcl) * NH + n) * HWN;
    }

    #pragma unroll
    for (int t = 0; t < TPC; ++t) {
        const int tile = ch * TPC + t;
        const int hwr = tile * 16 + (l & 15);
        const size_t abase = ((size_t)(b * HWN + hwr) * NH + n) * 64 + (l >> 4) * 8;
        const short8_t ah = *reinterpret_cast<const short8_t*>(kp_il + abase);
        const short8_t al = *reinterpret_cast<const short8_t*>(kp_il + abase + 32);
        const int hw4 = tile * 16 + (l >> 4) * 4;
        const i32x4_t mv = *reinterpret_cast<const i32x4_t*>(mask + b * HWN + hw4);
        const float m0 = mv.x ? 0.f : 1.f, m1 = mv.y ? 0.f : 1.f;
        const float m2 = mv.z ? 0.f : 1.f, m3 = mv.w ? 0.f : 1.f;
        #pragma unroll
        for (int tt = 0; tt < NQT; ++tt) {
            f32x4_t c = {0.f, 0.f, 0.f, 0.f};
            c = __builtin_amdgcn_mfma_f32_16x16x32_bf16(ah, bh[tt], c, 0, 0, 0);
            c = __builtin_amdgcn_mfma_f32_16x16x32_bf16(ah, bl[tt], c, 0, 0, 0);
            c = __builtin_amdgcn_mfma_f32_16x16x32_bf16(al, bh[tt], c, 0, 0, 0);
            const float is = isv[tt];
            f32x4_t rv;
            rv[0] = __expf(c[0]) * is * m0;
            rv[1] = __expf(c[1]) * is * m1;
            rv[2] = __expf(c[2]) * is * m2;
            rv[3] = __expf(c[3]) * is * m3;
            if (qok[tt])
                __builtin_nontemporal_store(rv,
                    reinterpret_cast<f32x4_t*>(optr[tt] + hw4));
        }
    }
}

// ---------------------------------------------------------------------------
extern "C" void kernel_launch(void* const* d_in, const int* in_sizes, int n_in,
                              void* d_out, int out_size, void* d_ws, size_t ws_size,
                              hipStream_t stream) {
    const float* q    = (const float*)d_in[0];
    const float* k    = (const float*)d_in[1];
    const int*   mask = (const int*)d_in[2];
    const float* qw   = (const float*)d_in[3];
    const float* qb   = (const float*)d_in[4];
    const float* kw   = (const float*)d_in[5];
    const float* kb   = (const float*)d_in[6];
    float* out = (float*)d_out;

    // ws layout (bytes) — total 42,193,600 B (proven footprint):
    char* wsb = (char*)d_ws;
    unsigned short* kp_il = (unsigned short*)wsb;                    // 40.96 MB
    unsigned short* qp_il = (unsigned short*)(wsb + 40960000);       // 1.2288 MB
    float* invS           = (float*)(wsb + 40960000 + 1228800);      // 4.8 KB

    // scratch parked in d_out (stream-ordered; P5 overwrites all of d_out):
    unsigned short* kwB_hi = (unsigned short*)d_out;
    unsigned short* kwB_lo = kwB_hi + 65536;
    unsigned short* qwB_hi = kwB_hi + 131072;
    unsigned short* qwB_lo = kwB_hi + 196608;
    float* partials = (float*)((char*)d_out + (4u << 20));           // 4.8 MB

    prep_kwB_kernel<<<dim3(16, 8), 64, 0, stream>>>(kw, kwB_hi, kwB_lo);
    prep_kwB_kernel<<<dim3(16, 8), 64, 0, stream>>>(qw, qwB_hi, qwB_lo);
    qproj_kernel<<<75, 256, 0, stream>>>(q, qwB_hi, qwB_lo, qb, qp_il);
    kproj_kernel<<<BB * NT, 256, 0, stream>>>(k, kwB_hi, kwB_lo, kb, kp_il);
    attn_stats_kernel<<<(BB * NH * NCHUNK * 2) / 4, 256, 0, stream>>>(
        qp_il, kp_il, mask, partials);
    invsum_kernel<<<BB * QQ, 64, 0, stream>>>(partials, invS);
    attn_out_kernel<<<(BB * NH * QCH * NCHUNK) / 4, 256, 0, stream>>>(
        qp_il, kp_il, mask, invS, out);
}